// Round 1
// baseline (421.232 us; speedup 1.0000x reference)
//
#include <hip/hip_runtime.h>

// Swin shifted-window attention, MI355X gfx950.
// f16 MFMA (16x16x32) everywhere, fp32 accumulate + fp32 softmax.
// Pipeline: k_qkv (gather+GEMM) -> k_attn (per-window attention) -> k_out (proj+scatter).
// d_out doubles as the q|k buffer (f16) until k_out overwrites it with fp32 output.

using f16   = _Float16;
using f16x8 = __attribute__((ext_vector_type(8))) _Float16;
using f16x4 = __attribute__((ext_vector_type(4))) _Float16;
using f32x4 = __attribute__((ext_vector_type(4))) float;

#define MFMA16(a, b, c) __builtin_amdgcn_mfma_f32_16x16x32_f16((a), (b), (c), 0, 0, 0)

static constexpr int QK_HALF = 65536 * 512;  // element offset of k-region inside d_out overlay

// token t (window-partition order, rolled frame) -> element offset of its patch row in x / out.
// Same mapping for input gather (roll -4 then partition) and output scatter (merge then roll +4).
__device__ __forceinline__ int tok2patch(int t) {
  int b = t >> 12, rem = t & 4095;
  int widx = rem >> 6, s = rem & 63;
  int pr = (((widx >> 3) << 3) + (s >> 3) + 4) & 63;
  int pc = (((widx & 7) << 3) + (s & 7) + 4) & 63;
  return ((b << 12) | (pr << 6) | pc) << 9;  // *512 channels
}

__device__ __forceinline__ f16x8 cvt8(float4 a, float4 b) {
  f16x8 h = { (f16)a.x, (f16)a.y, (f16)a.z, (f16)a.w,
              (f16)b.x, (f16)b.y, (f16)b.z, (f16)b.w };
  return h;
}

// ---------------------------------------------------------------------------
// Kernel 1: QKV projection.  C[t, n] = sum_k A[t,k] * Wqkv[n,k] + bqkv[n]
// A rows gathered via tok2patch (fp32 -> f16 on stage).  128x128 tile, BK=32.
// q,k -> d_out overlay (row-major f16); v -> vt transposed per (window, head).
// LDS layout [128][4 chunks of 16B], chunk XOR-swizzled by (row>>1)&3 so both
// staging writes and fragment ds_read_b128 stay at <=2-way bank conflicts.
// ---------------------------------------------------------------------------
__global__ __launch_bounds__(256) void k_qkv(const float* __restrict__ x,
                                             const float* __restrict__ wq,
                                             const float* __restrict__ bq,
                                             f16* __restrict__ qk,
                                             f16* __restrict__ vt) {
  __shared__ f16 As[128 * 32];
  __shared__ f16 Bs[128 * 32];
  __shared__ int rowoff[128];
  const int tid = threadIdx.x;
  const int bn = blockIdx.x;  // 0..11 (fastest -> column tiles share A panel in L2)
  const int bm = blockIdx.y;  // 0..511
  if (tid < 128) rowoff[tid] = tok2patch(bm * 128 + tid);
  __syncthreads();
  const int lane = tid & 63, wave = tid >> 6;
  const int jlo = lane & 15, g = lane >> 4;
  const int wrow = (wave >> 1) * 64, wcol = (wave & 1) * 64;

  // staging assignment: thread covers rows sr and sr+64, 16B chunk sc
  const int sr = tid >> 2, sc = tid & 3;
  const float* ax0 = x + rowoff[sr] + sc * 8;
  const float* ax1 = x + rowoff[sr + 64] + sc * 8;
  const float* bx0 = wq + (bn * 128 + sr) * 512 + sc * 8;
  const float* bx1 = bx0 + 64 * 512;
  f16* adst = (f16*)((char*)As + sr * 64 + 16 * (sc ^ ((sr >> 1) & 3)));
  f16* bdst = (f16*)((char*)Bs + sr * 64 + 16 * (sc ^ ((sr >> 1) & 3)));
  // row sr+64: same chunk swizzle ((sr+64)>>1 & 3 == (sr>>1)&3), +4096 bytes

  float4 r0, r1, r2, r3, r4, r5, r6, r7;
#define LOADT(K)                                                        \
  do {                                                                  \
    r0 = *(const float4*)(ax0 + (K)); r1 = *(const float4*)(ax0 + (K) + 4); \
    r2 = *(const float4*)(ax1 + (K)); r3 = *(const float4*)(ax1 + (K) + 4); \
    r4 = *(const float4*)(bx0 + (K)); r5 = *(const float4*)(bx0 + (K) + 4); \
    r6 = *(const float4*)(bx1 + (K)); r7 = *(const float4*)(bx1 + (K) + 4); \
  } while (0)

  f32x4 acc[4][4] = {};
  LOADT(0);
  for (int k0 = 0; k0 < 512; k0 += 32) {
    *(f16x8*)adst          = cvt8(r0, r1);
    *(f16x8*)(adst + 2048) = cvt8(r2, r3);
    *(f16x8*)bdst          = cvt8(r4, r5);
    *(f16x8*)(bdst + 2048) = cvt8(r6, r7);
    __syncthreads();
    if (k0 < 480) LOADT(k0 + 32);  // prefetch next K-step under the MFMAs
    f16x8 af[4], bf[4];
#pragma unroll
    for (int mt = 0; mt < 4; ++mt) {
      int m = wrow + mt * 16 + jlo;
      af[mt] = *(const f16x8*)((const char*)As + m * 64 + 16 * (g ^ ((m >> 1) & 3)));
    }
#pragma unroll
    for (int nt = 0; nt < 4; ++nt) {
      int n = wcol + nt * 16 + jlo;
      bf[nt] = *(const f16x8*)((const char*)Bs + n * 64 + 16 * (g ^ ((n >> 1) & 3)));
    }
#pragma unroll
    for (int mt = 0; mt < 4; ++mt)
#pragma unroll
      for (int nt = 0; nt < 4; ++nt)
        acc[mt][nt] = MFMA16(af[mt], bf[nt], acc[mt][nt]);
    __syncthreads();
  }
#undef LOADT

  // epilogue: D layout col = lane&15, row = (lane>>4)*4 + reg
#pragma unroll
  for (int nt = 0; nt < 4; ++nt) {
    const int colg = bn * 128 + wcol + nt * 16 + jlo;  // 0..1535
    const float bias = bq[colg];
    if (colg < 1024) {  // q or k -> row-major f16 into d_out overlay
      const int base = (colg < 512) ? colg : (colg - 512 + QK_HALF);
#pragma unroll
      for (int mt = 0; mt < 4; ++mt) {
        const int t0 = bm * 128 + wrow + mt * 16 + g * 4;
#pragma unroll
        for (int r = 0; r < 4; ++r)
          qk[base + (t0 + r) * 512] = (f16)(acc[mt][nt][r] + bias);
      }
    } else {  // v -> transposed per (window, head): vt[w][h][d][s]
      const int n = colg - 1024, h = n >> 5, d = n & 31;
#pragma unroll
      for (int mt = 0; mt < 4; ++mt) {
        const int t0 = bm * 128 + wrow + mt * 16 + g * 4;
        const int w = t0 >> 6, s0 = t0 & 63;  // 4 consecutive tokens stay in one window
        f16x4 pk = { (f16)(acc[mt][nt][0] + bias), (f16)(acc[mt][nt][1] + bias),
                     (f16)(acc[mt][nt][2] + bias), (f16)(acc[mt][nt][3] + bias) };
        *(f16x4*)(vt + ((w * 16 + h) * 32 + d) * 64 + s0) = pk;
      }
    }
  }
}

// ---------------------------------------------------------------------------
// Kernel 2: per-window attention.  1 block = 1 window (64 tokens), 4 waves,
// each wave owns 4 heads.  QK^T and PV via 16x16x32 f16 MFMA; fp32 softmax
// with analytic shift-mask; P relayout via per-wave LDS (stride 144B).
// ---------------------------------------------------------------------------
__global__ __launch_bounds__(256) void k_attn(const f16* __restrict__ qk,
                                              const f16* __restrict__ vt,
                                              f16* __restrict__ ao) {
  __shared__ f16 P[4][64 * 72];  // per-wave 64x64 P, row stride 72 halfs (144B)
  const int w = blockIdx.x;      // 0..1023
  const int widx = w & 63;
  const bool er = (widx >> 3) == 7;  // last row-window: rows a>=4 are group-2
  const bool ec = (widx & 7) == 7;   // last col-window: cols b>=4 are group-1
  const int tid = threadIdx.x;
  const int lane = tid & 63, wave = tid >> 6;
  const int jlo = lane & 15, g = lane >> 4;
  const int tb = w * 64;
  f16* Pw = P[wave];
  const float scale = 0.17677669529663687f;  // 32^-0.5

#pragma unroll 1
  for (int hh = 0; hh < 4; ++hh) {
    const int h = wave * 4 + hh;
    // fragment loads: A row = lane&15, k = (lane>>4)*8 + r (K-contiguous 16B)
    f16x8 qa[4], kb[4];
#pragma unroll
    for (int mt = 0; mt < 4; ++mt)
      qa[mt] = *(const f16x8*)(qk + (tb + mt * 16 + jlo) * 512 + h * 32 + g * 8);
#pragma unroll
    for (int nt = 0; nt < 4; ++nt)
      kb[nt] = *(const f16x8*)(qk + QK_HALF + (tb + nt * 16 + jlo) * 512 + h * 32 + g * 8);
    f32x4 sc[4][4] = {};
#pragma unroll
    for (int mt = 0; mt < 4; ++mt)
#pragma unroll
      for (int nt = 0; nt < 4; ++nt)
        sc[mt][nt] = MFMA16(qa[mt], kb[nt], sc[mt][nt]);

    // mask + scale + softmax (fp32). Row i lives in the 16-lane group sharing lane>>4.
    int gj[4];
#pragma unroll
    for (int nt = 0; nt < 4; ++nt) {
      int j = nt * 16 + jlo;
      gj[nt] = ((er && ((j >> 3) >= 4)) ? 2 : 0) | ((ec && ((j & 7) >= 4)) ? 1 : 0);
    }
    float rinv[4][4];
#pragma unroll
    for (int mt = 0; mt < 4; ++mt) {
#pragma unroll
      for (int r = 0; r < 4; ++r) {
        const int i = mt * 16 + g * 4 + r;
        const int gi = ((er && ((i >> 3) >= 4)) ? 2 : 0) | ((ec && ((i & 7) >= 4)) ? 1 : 0);
        float v0 = (gi == gj[0]) ? sc[mt][0][r] * scale : -1e9f;
        float v1 = (gi == gj[1]) ? sc[mt][1][r] * scale : -1e9f;
        float v2 = (gi == gj[2]) ? sc[mt][2][r] * scale : -1e9f;
        float v3 = (gi == gj[3]) ? sc[mt][3][r] * scale : -1e9f;
        float m = fmaxf(fmaxf(v0, v1), fmaxf(v2, v3));
        m = fmaxf(m, __shfl_xor(m, 1));
        m = fmaxf(m, __shfl_xor(m, 2));
        m = fmaxf(m, __shfl_xor(m, 4));
        m = fmaxf(m, __shfl_xor(m, 8));
        float p0 = __expf(v0 - m), p1 = __expf(v1 - m);
        float p2 = __expf(v2 - m), p3 = __expf(v3 - m);
        float s = p0 + p1 + p2 + p3;
        s += __shfl_xor(s, 1);
        s += __shfl_xor(s, 2);
        s += __shfl_xor(s, 4);
        s += __shfl_xor(s, 8);
        rinv[mt][r] = 1.0f / s;
        sc[mt][0][r] = p0; sc[mt][1][r] = p1; sc[mt][2][r] = p2; sc[mt][3][r] = p3;
      }
    }
    // P -> LDS (D layout scatter), then reread as A fragments. Same-wave DS is in-order.
#pragma unroll
    for (int mt = 0; mt < 4; ++mt)
#pragma unroll
      for (int nt = 0; nt < 4; ++nt)
#pragma unroll
        for (int r = 0; r < 4; ++r)
          Pw[(mt * 16 + g * 4 + r) * 72 + nt * 16 + jlo] = (f16)sc[mt][nt][r];
    asm volatile("s_waitcnt lgkmcnt(0)" ::: "memory");

    f32x4 o[4][2] = {};
#pragma unroll
    for (int ks = 0; ks < 2; ++ks) {
      f16x8 pa[4], vb[2];
#pragma unroll
      for (int mt = 0; mt < 4; ++mt)
        pa[mt] = *(const f16x8*)((const char*)Pw + (mt * 16 + jlo) * 144 + ks * 64 + g * 16);
#pragma unroll
      for (int nt = 0; nt < 2; ++nt)  // B[k][d] = V[k][d] = vt[d][k]: contiguous 16B
        vb[nt] = *(const f16x8*)(vt + ((w * 16 + h) * 32 + nt * 16 + jlo) * 64 + ks * 32 + g * 8);
#pragma unroll
      for (int mt = 0; mt < 4; ++mt)
#pragma unroll
        for (int nt = 0; nt < 2; ++nt)
          o[mt][nt] = MFMA16(pa[mt], vb[nt], o[mt][nt]);
    }
    // normalize rows + store merged-head layout ao[t][h*32+d]
#pragma unroll
    for (int mt = 0; mt < 4; ++mt)
#pragma unroll
      for (int nt = 0; nt < 2; ++nt)
#pragma unroll
        for (int r = 0; r < 4; ++r)
          ao[(tb + mt * 16 + g * 4 + r) * 512 + h * 32 + nt * 16 + jlo] =
              (f16)(o[mt][nt][r] * rinv[mt][r]);
  }
}

// ---------------------------------------------------------------------------
// Kernel 3: output projection + window-merge + roll(+4) scatter (fp32 out).
// Same GEMM skeleton as k_qkv; A is f16 (no conversion), B converted on stage.
// ---------------------------------------------------------------------------
__global__ __launch_bounds__(256) void k_out(const f16* __restrict__ ao,
                                             const float* __restrict__ wo,
                                             const float* __restrict__ bo,
                                             float* __restrict__ out) {
  __shared__ f16 As[128 * 32];
  __shared__ f16 Bs[128 * 32];
  __shared__ int rowoff[128];
  const int tid = threadIdx.x;
  const int bn = blockIdx.x;  // 0..3
  const int bm = blockIdx.y;  // 0..511
  if (tid < 128) rowoff[tid] = tok2patch(bm * 128 + tid);
  __syncthreads();
  const int lane = tid & 63, wave = tid >> 6;
  const int jlo = lane & 15, g = lane >> 4;
  const int wrow = (wave >> 1) * 64, wcol = (wave & 1) * 64;

  const int sr = tid >> 2, sc = tid & 3;
  const f16* ax0 = ao + (bm * 128 + sr) * 512 + sc * 8;
  const f16* ax1 = ax0 + 64 * 512;
  const float* bx0 = wo + (bn * 128 + sr) * 512 + sc * 8;
  const float* bx1 = bx0 + 64 * 512;
  f16* adst = (f16*)((char*)As + sr * 64 + 16 * (sc ^ ((sr >> 1) & 3)));
  f16* bdst = (f16*)((char*)Bs + sr * 64 + 16 * (sc ^ ((sr >> 1) & 3)));

  f16x8 ha0, ha1;
  float4 r4, r5, r6, r7;
#define LOADT(K)                                                        \
  do {                                                                  \
    ha0 = *(const f16x8*)(ax0 + (K)); ha1 = *(const f16x8*)(ax1 + (K)); \
    r4 = *(const float4*)(bx0 + (K)); r5 = *(const float4*)(bx0 + (K) + 4); \
    r6 = *(const float4*)(bx1 + (K)); r7 = *(const float4*)(bx1 + (K) + 4); \
  } while (0)

  f32x4 acc[4][4] = {};
  LOADT(0);
  for (int k0 = 0; k0 < 512; k0 += 32) {
    *(f16x8*)adst          = ha0;
    *(f16x8*)(adst + 2048) = ha1;
    *(f16x8*)bdst          = cvt8(r4, r5);
    *(f16x8*)(bdst + 2048) = cvt8(r6, r7);
    __syncthreads();
    if (k0 < 480) LOADT(k0 + 32);
    f16x8 af[4], bf[4];
#pragma unroll
    for (int mt = 0; mt < 4; ++mt) {
      int m = wrow + mt * 16 + jlo;
      af[mt] = *(const f16x8*)((const char*)As + m * 64 + 16 * (g ^ ((m >> 1) & 3)));
    }
#pragma unroll
    for (int nt = 0; nt < 4; ++nt) {
      int n = wcol + nt * 16 + jlo;
      bf[nt] = *(const f16x8*)((const char*)Bs + n * 64 + 16 * (g ^ ((n >> 1) & 3)));
    }
#pragma unroll
    for (int mt = 0; mt < 4; ++mt)
#pragma unroll
      for (int nt = 0; nt < 4; ++nt)
        acc[mt][nt] = MFMA16(af[mt], bf[nt], acc[mt][nt]);
    __syncthreads();
  }
#undef LOADT

#pragma unroll
  for (int nt = 0; nt < 4; ++nt) {
    const int colg = bn * 128 + wcol + nt * 16 + jlo;  // 0..511
    const float bias = bo[colg];
#pragma unroll
    for (int mt = 0; mt < 4; ++mt) {
#pragma unroll
      for (int r = 0; r < 4; ++r)
        out[rowoff[wrow + mt * 16 + g * 4 + r] + colg] = acc[mt][nt][r] + bias;
    }
  }
}

extern "C" void kernel_launch(void* const* d_in, const int* in_sizes, int n_in,
                              void* d_out, int out_size, void* d_ws, size_t ws_size,
                              hipStream_t stream) {
  const float* x  = (const float*)d_in[0];
  const float* wq = (const float*)d_in[1];
  const float* bq = (const float*)d_in[2];
  const float* wo = (const float*)d_in[3];
  const float* bo = (const float*)d_in[4];
  float* out = (float*)d_out;

  // d_out overlay: [q f16 64MiB | k f16 64MiB], fully rewritten by k_qkv each call,
  // fully overwritten (fp32) by k_out which never reads it.
  f16* qk = (f16*)d_out;
  // workspace: vt (V transposed, 64 MiB) + ao (attention output, 64 MiB) = 128 MiB
  f16* vt = (f16*)d_ws;
  f16* ao = (f16*)((char*)d_ws + (64u << 20));

  k_qkv<<<dim3(12, 512), 256, 0, stream>>>(x, wq, bq, qk, vt);
  k_attn<<<dim3(1024), 256, 0, stream>>>(qk, vt, ao);
  k_out<<<dim3(4, 512), 256, 0, stream>>>(ao, wo, bo, out);
}